// Round 9
// baseline (63.147 us; speedup 1.0000x reference)
//
#include <hip/hip_runtime.h>
#include <hip/hip_bf16.h>

#define B_   16
#define T_   8192
#define H_   256
#define C_   11
#define KCH  256            // chunks per batch
#define LCH  32             // steps per chunk (T_/KCH)
#define NC   (B_*KCH)       // total chunks

typedef __attribute__((ext_vector_type(8))) short short8;
typedef __attribute__((ext_vector_type(4))) float f32x4;

// ---------------------------------------------------------------------------
// K1: MFMA encoder + emissions + fused numerator (unchanged from r7).
// ---------------------------------------------------------------------------
__global__ __launch_bounds__(256) void k_em(
    const float* __restrict__ seq, const float* __restrict__ Wenc,
    const float* __restrict__ benc, const float* __restrict__ Wemit,
    const float* __restrict__ bemit, const float* __restrict__ trans,
    const float* __restrict__ startt, const float* __restrict__ endt,
    const int* __restrict__ lengths, const int* __restrict__ labels,
    unsigned short* __restrict__ expem, float* __restrict__ numpart,
    unsigned* __restrict__ counter)
{
    __shared__ float ldsWpack[2048];   // [256][8]: w0..w3, benc, pad
    __shared__ float ldsWemit[4096];   // [256][16]: Wemit padded
    __shared__ float red[4];
    int tid = threadIdx.x;
    if (blockIdx.x == 0 && tid == 0) counter[0] = 0;   // reset for k_comb

    for (int idx = tid; idx < 2048; idx += 256) {
        int h = idx >> 3, s = idx & 7;
        float v = 0.f;
        if (s < 4) v = Wenc[s * H_ + h];
        else if (s == 4) v = benc[h];
        ldsWpack[idx] = v;
    }
    for (int idx = tid; idx < 4096; idx += 256) {
        int h = idx >> 4, c = idx & 15;
        ldsWemit[idx] = (c < C_) ? Wemit[h * C_ + c] : 0.f;
    }
    __syncthreads();

    int wid = tid >> 6, lane = tid & 63;
    int g = lane >> 4, li = lane & 15;
    int b0 = blockIdx.x >> 5;                     // 32 blocks per batch
    int tb0 = (blockIdx.x & 31) * 256 + wid * 64; // wave covers 64 rows
    size_t grow0 = (size_t)b0 * T_ + tb0;

    float4 xs[4];
#pragma unroll
    for (int tt = 0; tt < 4; tt++)
        xs[tt] = *(const float4*)(seq + (grow0 + tt * 16 + li) * 4);

    f32x4 acc[4];
#pragma unroll
    for (int tt = 0; tt < 4; tt++) acc[tt] = (f32x4){0.f, 0.f, 0.f, 0.f};

#pragma unroll 1
    for (int kb = 0; kb < 8; kb++) {
        float We[8][5], wm[8];
#pragma unroll
        for (int e = 0; e < 8; e++) {
            int h = 32 * kb + 4 * g + (e & 3) + 16 * (e >> 2);
            float4 w4 = *(const float4*)&ldsWpack[h * 8];
            We[e][0] = w4.x; We[e][1] = w4.y; We[e][2] = w4.z; We[e][3] = w4.w;
            We[e][4] = ldsWpack[h * 8 + 4];
            wm[e] = ldsWemit[h * 16 + li];
        }
        unsigned a0, a1, a2, a3;
        asm("v_cvt_pk_bf16_f32 %0, %1, %2" : "=v"(a0) : "v"(wm[0]), "v"(wm[1]));
        asm("v_cvt_pk_bf16_f32 %0, %1, %2" : "=v"(a1) : "v"(wm[2]), "v"(wm[3]));
        asm("v_cvt_pk_bf16_f32 %0, %1, %2" : "=v"(a2) : "v"(wm[4]), "v"(wm[5]));
        asm("v_cvt_pk_bf16_f32 %0, %1, %2" : "=v"(a3) : "v"(wm[6]), "v"(wm[7]));
        union { short8 s8; uint4 u4; } au;
        au.u4 = make_uint4(a0, a1, a2, a3);

#pragma unroll
        for (int tt = 0; tt < 4; tt++) {
            float4 x = xs[tt];
            float hv[8];
#pragma unroll
            for (int e = 0; e < 8; e++) {
                float h = fmaf(x.x, We[e][0],
                          fmaf(x.y, We[e][1],
                          fmaf(x.z, We[e][2],
                          fmaf(x.w, We[e][3], We[e][4]))));
                hv[e] = fmaxf(h, 0.f);
            }
            unsigned u0, u1, u2, u3;
            asm("v_cvt_pk_bf16_f32 %0, %1, %2" : "=v"(u0) : "v"(hv[0]), "v"(hv[1]));
            asm("v_cvt_pk_bf16_f32 %0, %1, %2" : "=v"(u1) : "v"(hv[2]), "v"(hv[3]));
            asm("v_cvt_pk_bf16_f32 %0, %1, %2" : "=v"(u2) : "v"(hv[4]), "v"(hv[5]));
            asm("v_cvt_pk_bf16_f32 %0, %1, %2" : "=v"(u3) : "v"(hv[6]), "v"(hv[7]));
            union { short8 s8; uint4 u4; } bfu;
            bfu.u4 = make_uint4(u0, u1, u2, u3);
            acc[tt] = __builtin_amdgcn_mfma_f32_16x16x32_bf16(au.s8, bfu.s8, acc[tt], 0, 0, 0);
        }
    }

    int len = lengths[b0];
    const int* lab = labels + (size_t)b0 * T_;
    float bm[4];
#pragma unroll
    for (int r = 0; r < 4; r++) {
        int c = 4 * g + r;
        bm[r] = (c < C_) ? bemit[c] : 0.f;
    }

    float nacc = 0.f;
#pragma unroll
    for (int tt = 0; tt < 4; tt++) {
        float em0 = acc[tt].x + bm[0];
        float em1 = acc[tt].y + bm[1];
        float em2 = acc[tt].z + bm[2];
        float em3 = acc[tt].w + bm[3];

        int t = tb0 + tt * 16 + li;
        int tg = lab[t]; tg = tg < 0 ? 0 : tg;
        if (g == (tg >> 2) && t < len) {
            int r = tg & 3;
            float emtg = r == 0 ? em0 : r == 1 ? em1 : r == 2 ? em2 : em3;
            float contrib;
            if (t == 0) {
                contrib = startt[tg] + emtg;
            } else {
                int tp = lab[t - 1]; tp = tp < 0 ? 0 : tp;
                contrib = trans[tp * C_ + tg] + emtg;
            }
            if (t == len - 1) contrib += endt[tg];
            nacc += contrib;
        }

        if (g < 3) {
            float e0 = __expf(em0), e1 = __expf(em1);
            float e2 = __expf(em2), e3 = __expf(em3);
            unsigned u0, u1;
            asm("v_cvt_pk_bf16_f32 %0, %1, %2" : "=v"(u0) : "v"(e0), "v"(e1));
            asm("v_cvt_pk_bf16_f32 %0, %1, %2" : "=v"(u1) : "v"(e2), "v"(e3));
            *(uint2*)(expem + (grow0 + tt * 16 + li) * 16 + g * 4) = make_uint2(u0, u1);
        }
    }

#pragma unroll
    for (int off = 32; off > 0; off >>= 1) nacc += __shfl_down(nacc, off);
    if (lane == 0) red[wid] = nacc;
    __syncthreads();
    if (tid == 0) numpart[blockIdx.x] = red[0] + red[1] + red[2] + red[3];
}

// ---------------------------------------------------------------------------
// bf16 emission row load/unpack helpers
// ---------------------------------------------------------------------------
__device__ __forceinline__ void loadRow(const unsigned short* __restrict__ p,
                                        uint4& qa, uint2& qb) {
    qa = *(const uint4*)p;
    qb = *(const uint2*)(p + 8);
}
__device__ __forceinline__ void unpackRow(uint4 qa, uint2 qb, float* emv) {
    emv[0]  = __uint_as_float(qa.x << 16);
    emv[1]  = __uint_as_float(qa.x & 0xffff0000u);
    emv[2]  = __uint_as_float(qa.y << 16);
    emv[3]  = __uint_as_float(qa.y & 0xffff0000u);
    emv[4]  = __uint_as_float(qa.z << 16);
    emv[5]  = __uint_as_float(qa.z & 0xffff0000u);
    emv[6]  = __uint_as_float(qa.w << 16);
    emv[7]  = __uint_as_float(qa.w & 0xffff0000u);
    emv[8]  = __uint_as_float(qb.x << 16);
    emv[9]  = __uint_as_float(qb.x & 0xffff0000u);
    emv[10] = __uint_as_float(qb.y << 16);
}

// ---------------------------------------------------------------------------
// K2: per-chunk transfer matrices. NEW: group-of-4 software pipeline — issue
// the next su-group's 4 row loads (8 vmem instrs in flight) before the 4
// matvecs of the current group (load->use distance ~1280cy > ~900cy HBM miss);
// prologue rows issued BEFORE the ~1.5k-cy eT/expf table build. Math order
// identical to r7 (absmax must stay 0.0).
// ---------------------------------------------------------------------------
__global__ __launch_bounds__(64, 1) void k_chunks(
    const float* __restrict__ trans, const int* __restrict__ lengths,
    const unsigned short* __restrict__ expem, float* __restrict__ G)
{
    int lane = threadIdx.x;
    int ciw = lane / C_;            // 5 chunks per wave (55/64 lanes)
    int i = lane - ciw * C_;
    int cid = blockIdx.x * 5 + ciw;
    if (ciw >= 5 || cid >= NC) return;

    int b = cid >> 8;
    int k = cid & (KCH - 1);
    int t0 = 1 + k * LCH;
    int len = lengths[b];
    float* o = G + (size_t)cid * 132 + i * 12;

    if (t0 >= len) {                 // fully inactive -> identity
#pragma unroll
        for (int j = 0; j < C_; j++) o[j] = (j == i) ? 1.f : 0.f;
        o[11] = 0.f;
        return;
    }

    const unsigned short* emb = expem + (size_t)b * T_ * 16;
    bool full = (t0 + LCH <= len);

    if (full) {
        // issue first-group loads BEFORE the expf table (overlap latency)
        uint4 Ra[4]; uint2 Rb[4];
#pragma unroll
        for (int q = 0; q < 4; q++)
            loadRow(emb + (size_t)(t0 + q) * 16, Ra[q], Rb[q]);

        float eT[121];
#pragma unroll
        for (int z = 0; z < 121; z++) eT[z] = __expf(trans[z]);
#pragma unroll
        for (int z = 0; z < 121; z++) asm volatile("" : "+v"(eT[z]));  // pin

        float g[C_];
#pragma unroll
        for (int j = 0; j < C_; j++) g[j] = (j == i) ? 1.f : 0.f;
        float ls = 0.f;

#pragma unroll 1
        for (int su = 0; su < LCH / 4; su++) {
            uint4 Na[4]; uint2 Nb[4];
            if (su < LCH / 4 - 1) {
                int tb = t0 + su * 4 + 4;
#pragma unroll
                for (int q = 0; q < 4; q++)
                    loadRow(emb + (size_t)(tb + q) * 16, Na[q], Nb[q]);
            }
#pragma unroll
            for (int ss = 0; ss < 4; ss++) {
                float emv[C_];
                unpackRow(Ra[ss], Rb[ss], emv);
                float nxt[C_];
#pragma unroll
                for (int j = 0; j < C_; j++) nxt[j] = g[0] * eT[j];
#pragma unroll
                for (int kk = 1; kk < C_; kk++)
#pragma unroll
                    for (int j = 0; j < C_; j++)
                        nxt[j] = fmaf(g[kk], eT[kk * C_ + j], nxt[j]);
#pragma unroll
                for (int j = 0; j < C_; j++) g[j] = nxt[j] * emv[j];
            }
            float s = 0.f;
#pragma unroll
            for (int j = 0; j < C_; j++) s += g[j];
            float r = 1.f / s;
#pragma unroll
            for (int j = 0; j < C_; j++) g[j] *= r;
            ls += __logf(s);
            if (su < LCH / 4 - 1) {
#pragma unroll
                for (int q = 0; q < 4; q++) { Ra[q] = Na[q]; Rb[q] = Nb[q]; }
            }
        }

#pragma unroll
        for (int j = 0; j < C_; j++) o[j] = g[j];
        o[11] = ls;
    } else {                          // boundary chunk (rare, ≤1 per batch)
        float eT[121];
#pragma unroll
        for (int z = 0; z < 121; z++) eT[z] = __expf(trans[z]);
#pragma unroll
        for (int z = 0; z < 121; z++) asm volatile("" : "+v"(eT[z]));

        float g[C_];
#pragma unroll
        for (int j = 0; j < C_; j++) g[j] = (j == i) ? 1.f : 0.f;
        float ls = 0.f;

#pragma unroll 1
        for (int su = 0; su < LCH / 4; su++) {
#pragma unroll
            for (int ss = 0; ss < 4; ss++) {
                int t = t0 + su * 4 + ss;
                int tc = (t < T_) ? t : (T_ - 1);
                uint4 ca; uint2 cb;
                loadRow(emb + (size_t)tc * 16, ca, cb);
                float emv[C_];
                unpackRow(ca, cb, emv);
                float nxt[C_];
#pragma unroll
                for (int j = 0; j < C_; j++) nxt[j] = g[0] * eT[j];
#pragma unroll
                for (int kk = 1; kk < C_; kk++)
#pragma unroll
                    for (int j = 0; j < C_; j++)
                        nxt[j] = fmaf(g[kk], eT[kk * C_ + j], nxt[j]);
                bool act = (t < len);
#pragma unroll
                for (int j = 0; j < C_; j++) g[j] = act ? nxt[j] * emv[j] : g[j];
            }
            float s = 0.f;
#pragma unroll
            for (int j = 0; j < C_; j++) s += g[j];
            float r = 1.f / s;
#pragma unroll
            for (int j = 0; j < C_; j++) g[j] *= r;
            ls += __logf(s);
        }

#pragma unroll
        for (int j = 0; j < C_; j++) o[j] = g[j];
        o[11] = ls;
    }
}

// ---------------------------------------------------------------------------
// K3: per-batch LDS tree combine + den + fused final reduction (r7 structure;
// staging unroll bumped).
// ---------------------------------------------------------------------------
__global__ __launch_bounds__(512, 1) void k_comb(
    const float* __restrict__ startt, const float* __restrict__ endt,
    const unsigned short* __restrict__ expem, const float* __restrict__ G0,
    const float* __restrict__ numpart, float* __restrict__ dens,
    unsigned* __restrict__ counter, float* __restrict__ out)
{
    __shared__ float M[KCH * 132];     // 135168 bytes
    int b = blockIdx.x, tid = threadIdx.x;

    float numb = 0.f;
    if (tid < 64) {
        float v = (tid < 32) ? numpart[b * 32 + tid] : 0.f;
#pragma unroll
        for (int off = 32; off > 0; off >>= 1) v += __shfl_down(v, off);
        numb = v;                       // valid on tid 0
    }

    const float4* src = (const float4*)(G0 + (size_t)b * KCH * 132);
    float4* dst = (float4*)M;
#pragma unroll 4
    for (int idx = tid; idx < KCH * 132 / 4; idx += 512) dst[idx] = src[idx];
    __syncthreads();

    for (int stride = 1; stride < KCH; stride <<= 1) {
        int npair = KCH / (2 * stride);
        for (int task = tid; task < npair * C_; task += 512) {
            int p = task / C_, i = task - p * C_;
            float* A  = M + (size_t)(2 * stride * p) * 132;
            float* Bm = M + (size_t)(2 * stride * p + stride) * 132;
            float a[C_];
#pragma unroll
            for (int kk = 0; kk < C_; kk++) a[kk] = A[i * 12 + kk];
            float als = A[i * 12 + 11];
            float m = Bm[11];
#pragma unroll
            for (int kk = 1; kk < C_; kk++) m = fmaxf(m, Bm[kk * 12 + 11]);
            float wv[C_];
#pragma unroll
            for (int kk = 0; kk < C_; kk++)
                wv[kk] = a[kk] * __expf(Bm[kk * 12 + 11] - m);
            float outv[C_];
#pragma unroll
            for (int j = 0; j < C_; j++) outv[j] = wv[0] * Bm[j];
#pragma unroll
            for (int kk = 1; kk < C_; kk++)
#pragma unroll
                for (int j = 0; j < C_; j++)
                    outv[j] = fmaf(wv[kk], Bm[kk * 12 + j], outv[j]);
            float s = 0.f;
#pragma unroll
            for (int j = 0; j < C_; j++) s += outv[j];
            float rr = 1.f / s;
#pragma unroll
            for (int j = 0; j < C_; j++) A[i * 12 + j] = outv[j] * rr;
            A[i * 12 + 11] = als + m + __logf(s);
        }
        __syncthreads();
    }

    if (tid == 0) {
        const float* Cm = M;
        const unsigned short* em0 = expem + (size_t)b * T_ * 16;
        float av[C_];
        float mm = -1e30f;
#pragma unroll
        for (int i2 = 0; i2 < C_; i2++) {
            float e0 = __uint_as_float((unsigned)em0[i2] << 16);
            av[i2] = startt[i2] + __logf(e0) + Cm[i2 * 12 + 11];
            mm = fmaxf(mm, av[i2]);
        }
        float S[C_];
#pragma unroll
        for (int j = 0; j < C_; j++) S[j] = 0.f;
#pragma unroll
        for (int i2 = 0; i2 < C_; i2++) {
            float e = __expf(av[i2] - mm);
#pragma unroll
            for (int j = 0; j < C_; j++) S[j] = fmaf(e, Cm[i2 * 12 + j], S[j]);
        }
        float tot = 0.f;
#pragma unroll
        for (int j = 0; j < C_; j++) tot += S[j] * __expf(endt[j]);
        float den = __logf(tot) + mm;

        float loss = numb - den;
        __hip_atomic_store(&dens[b], loss, __ATOMIC_RELEASE, __HIP_MEMORY_SCOPE_AGENT);
        unsigned old = __hip_atomic_fetch_add(counter, 1u, __ATOMIC_ACQ_REL,
                                              __HIP_MEMORY_SCOPE_AGENT);
        if (old == B_ - 1) {            // last block: fixed-order sum (deterministic)
            float s = 0.f;
#pragma unroll
            for (int j = 0; j < B_; j++)
                s += __hip_atomic_load(&dens[j], __ATOMIC_ACQUIRE,
                                       __HIP_MEMORY_SCOPE_AGENT);
            out[0] = -s / (float)B_;
        }
    }
}

extern "C" void kernel_launch(void* const* d_in, const int* in_sizes, int n_in,
                              void* d_out, int out_size, void* d_ws, size_t ws_size,
                              hipStream_t stream) {
    const float* seq    = (const float*)d_in[0];
    const float* Wenc   = (const float*)d_in[1];
    const float* benc   = (const float*)d_in[2];
    const float* Wemit  = (const float*)d_in[3];
    const float* bemit  = (const float*)d_in[4];
    const float* startt = (const float*)d_in[5];
    const float* trans  = (const float*)d_in[6];
    const float* endt   = (const float*)d_in[7];
    const int*   lengths= (const int*)d_in[8];
    const int*   labels = (const int*)d_in[9];

    char* w = (char*)d_ws;
    unsigned short* expem  = (unsigned short*)w;            // B*T*16 bf16 = 4,194,304 B
    float*          G0     = (float*)(w + 4194304);         // NC*132 f32  = 2,162,688 B
    float*          numpart= (float*)(w + 6356992);         // 512 f32
    float*          dens   = (float*)(w + 6359040);         // 16 f32
    unsigned*       counter= (unsigned*)(w + 6359104);      // 1 u32
    float*          out    = (float*)d_out;

    k_em<<<512, 256, 0, stream>>>(seq, Wenc, benc, Wemit, bemit, trans,
                                  startt, endt, lengths, labels,
                                  expem, numpart, counter);
    k_chunks<<<(NC + 4) / 5, 64, 0, stream>>>(trans, lengths, expem, G0);
    k_comb<<<B_, 512, 0, stream>>>(startt, endt, expem, G0, numpart,
                                   dens, counter, out);
}

// Round 10
// 47.005 us; speedup vs baseline: 1.3434x; 1.3434x over previous
//
#include <hip/hip_runtime.h>
#include <hip/hip_bf16.h>

#define B_   16
#define T_   8192
#define H_   256
#define C_   11
#define KCH  256            // chunks per batch
#define LCH  32             // steps per chunk (T_/KCH)
#define NC   (B_*KCH)       // total chunks

typedef __attribute__((ext_vector_type(8))) short short8;
typedef __attribute__((ext_vector_type(4))) float f32x4;

// ---------------------------------------------------------------------------
// K1: MFMA encoder + emissions + fused numerator (unchanged from r7).
// ---------------------------------------------------------------------------
__global__ __launch_bounds__(256) void k_em(
    const float* __restrict__ seq, const float* __restrict__ Wenc,
    const float* __restrict__ benc, const float* __restrict__ Wemit,
    const float* __restrict__ bemit, const float* __restrict__ trans,
    const float* __restrict__ startt, const float* __restrict__ endt,
    const int* __restrict__ lengths, const int* __restrict__ labels,
    unsigned short* __restrict__ expem, float* __restrict__ numpart,
    unsigned* __restrict__ counter)
{
    __shared__ float ldsWpack[2048];   // [256][8]: w0..w3, benc, pad
    __shared__ float ldsWemit[4096];   // [256][16]: Wemit padded
    __shared__ float red[4];
    int tid = threadIdx.x;
    if (blockIdx.x == 0 && tid == 0) counter[0] = 0;   // reset for k_comb

    for (int idx = tid; idx < 2048; idx += 256) {
        int h = idx >> 3, s = idx & 7;
        float v = 0.f;
        if (s < 4) v = Wenc[s * H_ + h];
        else if (s == 4) v = benc[h];
        ldsWpack[idx] = v;
    }
    for (int idx = tid; idx < 4096; idx += 256) {
        int h = idx >> 4, c = idx & 15;
        ldsWemit[idx] = (c < C_) ? Wemit[h * C_ + c] : 0.f;
    }
    __syncthreads();

    int wid = tid >> 6, lane = tid & 63;
    int g = lane >> 4, li = lane & 15;
    int b0 = blockIdx.x >> 5;                     // 32 blocks per batch
    int tb0 = (blockIdx.x & 31) * 256 + wid * 64; // wave covers 64 rows
    size_t grow0 = (size_t)b0 * T_ + tb0;

    float4 xs[4];
#pragma unroll
    for (int tt = 0; tt < 4; tt++)
        xs[tt] = *(const float4*)(seq + (grow0 + tt * 16 + li) * 4);

    f32x4 acc[4];
#pragma unroll
    for (int tt = 0; tt < 4; tt++) acc[tt] = (f32x4){0.f, 0.f, 0.f, 0.f};

#pragma unroll 1
    for (int kb = 0; kb < 8; kb++) {
        float We[8][5], wm[8];
#pragma unroll
        for (int e = 0; e < 8; e++) {
            int h = 32 * kb + 4 * g + (e & 3) + 16 * (e >> 2);
            float4 w4 = *(const float4*)&ldsWpack[h * 8];
            We[e][0] = w4.x; We[e][1] = w4.y; We[e][2] = w4.z; We[e][3] = w4.w;
            We[e][4] = ldsWpack[h * 8 + 4];
            wm[e] = ldsWemit[h * 16 + li];
        }
        unsigned a0, a1, a2, a3;
        asm("v_cvt_pk_bf16_f32 %0, %1, %2" : "=v"(a0) : "v"(wm[0]), "v"(wm[1]));
        asm("v_cvt_pk_bf16_f32 %0, %1, %2" : "=v"(a1) : "v"(wm[2]), "v"(wm[3]));
        asm("v_cvt_pk_bf16_f32 %0, %1, %2" : "=v"(a2) : "v"(wm[4]), "v"(wm[5]));
        asm("v_cvt_pk_bf16_f32 %0, %1, %2" : "=v"(a3) : "v"(wm[6]), "v"(wm[7]));
        union { short8 s8; uint4 u4; } au;
        au.u4 = make_uint4(a0, a1, a2, a3);

#pragma unroll
        for (int tt = 0; tt < 4; tt++) {
            float4 x = xs[tt];
            float hv[8];
#pragma unroll
            for (int e = 0; e < 8; e++) {
                float h = fmaf(x.x, We[e][0],
                          fmaf(x.y, We[e][1],
                          fmaf(x.z, We[e][2],
                          fmaf(x.w, We[e][3], We[e][4]))));
                hv[e] = fmaxf(h, 0.f);
            }
            unsigned u0, u1, u2, u3;
            asm("v_cvt_pk_bf16_f32 %0, %1, %2" : "=v"(u0) : "v"(hv[0]), "v"(hv[1]));
            asm("v_cvt_pk_bf16_f32 %0, %1, %2" : "=v"(u1) : "v"(hv[2]), "v"(hv[3]));
            asm("v_cvt_pk_bf16_f32 %0, %1, %2" : "=v"(u2) : "v"(hv[4]), "v"(hv[5]));
            asm("v_cvt_pk_bf16_f32 %0, %1, %2" : "=v"(u3) : "v"(hv[6]), "v"(hv[7]));
            union { short8 s8; uint4 u4; } bfu;
            bfu.u4 = make_uint4(u0, u1, u2, u3);
            acc[tt] = __builtin_amdgcn_mfma_f32_16x16x32_bf16(au.s8, bfu.s8, acc[tt], 0, 0, 0);
        }
    }

    int len = lengths[b0];
    const int* lab = labels + (size_t)b0 * T_;
    float bm[4];
#pragma unroll
    for (int r = 0; r < 4; r++) {
        int c = 4 * g + r;
        bm[r] = (c < C_) ? bemit[c] : 0.f;
    }

    float nacc = 0.f;
#pragma unroll
    for (int tt = 0; tt < 4; tt++) {
        float em0 = acc[tt].x + bm[0];
        float em1 = acc[tt].y + bm[1];
        float em2 = acc[tt].z + bm[2];
        float em3 = acc[tt].w + bm[3];

        int t = tb0 + tt * 16 + li;
        int tg = lab[t]; tg = tg < 0 ? 0 : tg;
        if (g == (tg >> 2) && t < len) {
            int r = tg & 3;
            float emtg = r == 0 ? em0 : r == 1 ? em1 : r == 2 ? em2 : em3;
            float contrib;
            if (t == 0) {
                contrib = startt[tg] + emtg;
            } else {
                int tp = lab[t - 1]; tp = tp < 0 ? 0 : tp;
                contrib = trans[tp * C_ + tg] + emtg;
            }
            if (t == len - 1) contrib += endt[tg];
            nacc += contrib;
        }

        if (g < 3) {
            float e0 = __expf(em0), e1 = __expf(em1);
            float e2 = __expf(em2), e3 = __expf(em3);
            unsigned u0, u1;
            asm("v_cvt_pk_bf16_f32 %0, %1, %2" : "=v"(u0) : "v"(e0), "v"(e1));
            asm("v_cvt_pk_bf16_f32 %0, %1, %2" : "=v"(u1) : "v"(e2), "v"(e3));
            *(uint2*)(expem + (grow0 + tt * 16 + li) * 16 + g * 4) = make_uint2(u0, u1);
        }
    }

#pragma unroll
    for (int off = 32; off > 0; off >>= 1) nacc += __shfl_down(nacc, off);
    if (lane == 0) red[wid] = nacc;
    __syncthreads();
    if (tid == 0) numpart[blockIdx.x] = red[0] + red[1] + red[2] + red[3];
}

// ---------------------------------------------------------------------------
// K2: MFMA chunk scan. One wave = one chunk. P = G^T lives in the accumulator;
// A = eT^T is a FIXED 2-dword bf16 fragment (the 121-float table is GONE —
// r4/r9 spill failure mode eliminated). Key layout fact (confirmed by k_em's
// absmax 0.0): C/D (row=4g+reg, col=lane&15) == B-frag (k=4g+(e&3), n=lane&15)
// for k<16 => next step's B operand is built from acc with NO cross-lane ops:
// b[e] = bf16(acc[e] * em[4g+e]). Rescale = column sum via 2 shfl_xor.
// Masked tail = identity = early stop (wave-uniform). Em rows prefetched one
// 4-step group ahead (~1.3k cy > L3 latency).
// ---------------------------------------------------------------------------
__global__ __launch_bounds__(256) void k_chunks(
    const float* __restrict__ trans, const int* __restrict__ lengths,
    const unsigned short* __restrict__ expem, float* __restrict__ G)
{
    int tid = threadIdx.x;
    int wave = tid >> 6, lane = tid & 63;
    int i = lane & 15, g = lane >> 4;          // P column i, k-group g
    int cid = (blockIdx.x << 2) | wave;        // 1024 blocks x 4 waves = 4096
    int b = cid >> 8, k = cid & (KCH - 1);
    int t0 = 1 + k * LCH;
    int len = lengths[b];
    bool writer = (i < C_) && (g < 3);
    float* o = G + (size_t)cid * 132 + i * 12 + 4 * g;

    if (t0 >= len) {                            // fully inactive -> identity
        if (writer) {
            float4 v;
            v.x = (4 * g + 0 == i) ? 1.f : 0.f;
            v.y = (4 * g + 1 == i) ? 1.f : 0.f;
            v.z = (4 * g + 2 == i) ? 1.f : 0.f;
            v.w = (g == 2) ? 0.f : ((4 * g + 3 == i) ? 1.f : 0.f);
            *(float4*)o = v;
        }
        return;
    }

    const unsigned short* emp = expem + ((size_t)b * T_ + t0) * 16 + 4 * g;

    // prologue: issue group-0 em loads before the exp chain
    uint2 Ld[4], Nd[4];
#pragma unroll
    for (int q = 0; q < 4; q++)
        Ld[q] = *(const uint2*)(emp + (size_t)q * 16);

    // A-frag: A[j=i][k=4g+(e&3)] = eT[k][j] = exp(trans[k*C+j]); 0 pad
    float af[4];
#pragma unroll
    for (int e = 0; e < 4; e++) {
        int kk = 4 * g + e;
        af[e] = (i < C_ && kk < C_) ? __expf(trans[kk * C_ + i]) : 0.f;
    }
    unsigned a0, a1;
    asm("v_cvt_pk_bf16_f32 %0, %1, %2" : "=v"(a0) : "v"(af[0]), "v"(af[1]));
    asm("v_cvt_pk_bf16_f32 %0, %1, %2" : "=v"(a1) : "v"(af[2]), "v"(af[3]));
    union { short8 s8; uint4 u4; } A; A.u4 = make_uint4(a0, a1, 0u, 0u);

    // P state fp32: p[e] = P[4g+e][i], init 16x16 identity (cols i>=11 dummy
    // but positive -> no NaN; never written)
    float p0 = (4 * g + 0 == i) ? 1.f : 0.f;
    float p1 = (4 * g + 1 == i) ? 1.f : 0.f;
    float p2 = (4 * g + 2 == i) ? 1.f : 0.f;
    float p3 = (4 * g + 3 == i) ? 1.f : 0.f;
    float ls = 0.f;

    int tl = t0 + LCH; if (len < tl) tl = len;  // early-stop bound

#pragma unroll 1
    for (int su = 0; su < LCH / 4; su++) {
        if (su < LCH / 4 - 1) {
#pragma unroll
            for (int q = 0; q < 4; q++)
                Nd[q] = *(const uint2*)(emp + (size_t)((su + 1) * 4 + q) * 16);
        }
#pragma unroll
        for (int ss = 0; ss < 4; ss++) {
            int t = t0 + su * 4 + ss;
            if (t < tl) {                        // wave-uniform
                unsigned b0u, b1u;
                asm("v_cvt_pk_bf16_f32 %0, %1, %2" : "=v"(b0u) : "v"(p0), "v"(p1));
                asm("v_cvt_pk_bf16_f32 %0, %1, %2" : "=v"(b1u) : "v"(p2), "v"(p3));
                union { short8 s8; uint4 u4; } Bf; Bf.u4 = make_uint4(b0u, b1u, 0u, 0u);
                f32x4 acc = __builtin_amdgcn_mfma_f32_16x16x32_bf16(
                    A.s8, Bf.s8, (f32x4){0.f, 0.f, 0.f, 0.f}, 0, 0, 0);
                uint2 emu = Ld[ss];
                p0 = acc.x * __uint_as_float(emu.x << 16);
                p1 = acc.y * __uint_as_float(emu.x & 0xffff0000u);
                p2 = acc.z * __uint_as_float(emu.y << 16);
                p3 = acc.w * __uint_as_float(emu.y & 0xffff0000u);
            }
        }
        // per-group rescale: s_i = sum over column i of P (lanes i,16+i,32+i,48+i)
        float part = (p0 + p1) + (p2 + p3);
        part += __shfl_xor(part, 16);
        part += __shfl_xor(part, 32);
        float r = 1.f / part;
        p0 *= r; p1 *= r; p2 *= r; p3 *= r;
        ls += __logf(part);
        if (su < LCH / 4 - 1) {
#pragma unroll
            for (int q = 0; q < 4; q++) Ld[q] = Nd[q];
        }
    }

    if (writer) {
        float w3 = (g == 2) ? ls : p3;           // j=11 slot holds ls
        *(float4*)o = make_float4(p0, p1, p2, w3);
    }
}

// ---------------------------------------------------------------------------
// K3: per-batch LDS tree combine + den + fused final reduction (unchanged).
// ---------------------------------------------------------------------------
__global__ __launch_bounds__(512, 1) void k_comb(
    const float* __restrict__ startt, const float* __restrict__ endt,
    const unsigned short* __restrict__ expem, const float* __restrict__ G0,
    const float* __restrict__ numpart, float* __restrict__ dens,
    unsigned* __restrict__ counter, float* __restrict__ out)
{
    __shared__ float M[KCH * 132];     // 135168 bytes
    int b = blockIdx.x, tid = threadIdx.x;

    float numb = 0.f;
    if (tid < 64) {
        float v = (tid < 32) ? numpart[b * 32 + tid] : 0.f;
#pragma unroll
        for (int off = 32; off > 0; off >>= 1) v += __shfl_down(v, off);
        numb = v;                       // valid on tid 0
    }

    const float4* src = (const float4*)(G0 + (size_t)b * KCH * 132);
    float4* dst = (float4*)M;
#pragma unroll 4
    for (int idx = tid; idx < KCH * 132 / 4; idx += 512) dst[idx] = src[idx];
    __syncthreads();

    for (int stride = 1; stride < KCH; stride <<= 1) {
        int npair = KCH / (2 * stride);
        for (int task = tid; task < npair * C_; task += 512) {
            int p = task / C_, i = task - p * C_;
            float* A  = M + (size_t)(2 * stride * p) * 132;
            float* Bm = M + (size_t)(2 * stride * p + stride) * 132;
            float a[C_];
#pragma unroll
            for (int kk = 0; kk < C_; kk++) a[kk] = A[i * 12 + kk];
            float als = A[i * 12 + 11];
            float m = Bm[11];
#pragma unroll
            for (int kk = 1; kk < C_; kk++) m = fmaxf(m, Bm[kk * 12 + 11]);
            float wv[C_];
#pragma unroll
            for (int kk = 0; kk < C_; kk++)
                wv[kk] = a[kk] * __expf(Bm[kk * 12 + 11] - m);
            float outv[C_];
#pragma unroll
            for (int j = 0; j < C_; j++) outv[j] = wv[0] * Bm[j];
#pragma unroll
            for (int kk = 1; kk < C_; kk++)
#pragma unroll
                for (int j = 0; j < C_; j++)
                    outv[j] = fmaf(wv[kk], Bm[kk * 12 + j], outv[j]);
            float s = 0.f;
#pragma unroll
            for (int j = 0; j < C_; j++) s += outv[j];
            float rr = 1.f / s;
#pragma unroll
            for (int j = 0; j < C_; j++) A[i * 12 + j] = outv[j] * rr;
            A[i * 12 + 11] = als + m + __logf(s);
        }
        __syncthreads();
    }

    if (tid == 0) {
        const float* Cm = M;
        const unsigned short* em0 = expem + (size_t)b * T_ * 16;
        float av[C_];
        float mm = -1e30f;
#pragma unroll
        for (int i2 = 0; i2 < C_; i2++) {
            float e0 = __uint_as_float((unsigned)em0[i2] << 16);
            av[i2] = startt[i2] + __logf(e0) + Cm[i2 * 12 + 11];
            mm = fmaxf(mm, av[i2]);
        }
        float S[C_];
#pragma unroll
        for (int j = 0; j < C_; j++) S[j] = 0.f;
#pragma unroll
        for (int i2 = 0; i2 < C_; i2++) {
            float e = __expf(av[i2] - mm);
#pragma unroll
            for (int j = 0; j < C_; j++) S[j] = fmaf(e, Cm[i2 * 12 + j], S[j]);
        }
        float tot = 0.f;
#pragma unroll
        for (int j = 0; j < C_; j++) tot += S[j] * __expf(endt[j]);
        float den = __logf(tot) + mm;

        float loss = numb - den;
        __hip_atomic_store(&dens[b], loss, __ATOMIC_RELEASE, __HIP_MEMORY_SCOPE_AGENT);
        unsigned old = __hip_atomic_fetch_add(counter, 1u, __ATOMIC_ACQ_REL,
                                              __HIP_MEMORY_SCOPE_AGENT);
        if (old == B_ - 1) {            // last block: fixed-order sum (deterministic)
            float s = 0.f;
#pragma unroll
            for (int j = 0; j < B_; j++)
                s += __hip_atomic_load(&dens[j], __ATOMIC_ACQUIRE,
                                       __HIP_MEMORY_SCOPE_AGENT);
            out[0] = -s / (float)B_;
        }
    }
}

extern "C" void kernel_launch(void* const* d_in, const int* in_sizes, int n_in,
                              void* d_out, int out_size, void* d_ws, size_t ws_size,
                              hipStream_t stream) {
    const float* seq    = (const float*)d_in[0];
    const float* Wenc   = (const float*)d_in[1];
    const float* benc   = (const float*)d_in[2];
    const float* Wemit  = (const float*)d_in[3];
    const float* bemit  = (const float*)d_in[4];
    const float* startt = (const float*)d_in[5];
    const float* trans  = (const float*)d_in[6];
    const float* endt   = (const float*)d_in[7];
    const int*   lengths= (const int*)d_in[8];
    const int*   labels = (const int*)d_in[9];

    char* w = (char*)d_ws;
    unsigned short* expem  = (unsigned short*)w;            // B*T*16 bf16 = 4,194,304 B
    float*          G0     = (float*)(w + 4194304);         // NC*132 f32  = 2,162,688 B
    float*          numpart= (float*)(w + 6356992);         // 512 f32
    float*          dens   = (float*)(w + 6359040);         // 16 f32
    unsigned*       counter= (unsigned*)(w + 6359104);      // 1 u32
    float*          out    = (float*)d_out;

    k_em<<<512, 256, 0, stream>>>(seq, Wenc, benc, Wemit, bemit, trans,
                                  startt, endt, lengths, labels,
                                  expem, numpart, counter);
    k_chunks<<<1024, 256, 0, stream>>>(trans, lengths, expem, G0);
    k_comb<<<B_, 512, 0, stream>>>(startt, endt, expem, G0, numpart,
                                   dens, counter, out);
}

// Round 11
// 45.231 us; speedup vs baseline: 1.3961x; 1.0392x over previous
//
#include <hip/hip_runtime.h>
#include <hip/hip_bf16.h>

#define B_   16
#define T_   8192
#define H_   256
#define C_   11
#define KCH  256            // chunks per batch
#define LCH  32             // steps per chunk (T_/KCH)
#define KL   64             // leaves per batch after in-block 4->1 pre-combine

typedef __attribute__((ext_vector_type(8))) short short8;
typedef __attribute__((ext_vector_type(4))) float f32x4;

// ---------------------------------------------------------------------------
// K1: MFMA encoder + emissions + fused numerator (unchanged from r7).
// ---------------------------------------------------------------------------
__global__ __launch_bounds__(256) void k_em(
    const float* __restrict__ seq, const float* __restrict__ Wenc,
    const float* __restrict__ benc, const float* __restrict__ Wemit,
    const float* __restrict__ bemit, const float* __restrict__ trans,
    const float* __restrict__ startt, const float* __restrict__ endt,
    const int* __restrict__ lengths, const int* __restrict__ labels,
    unsigned short* __restrict__ expem, float* __restrict__ numpart,
    unsigned* __restrict__ counter)
{
    __shared__ float ldsWpack[2048];   // [256][8]: w0..w3, benc, pad
    __shared__ float ldsWemit[4096];   // [256][16]: Wemit padded
    __shared__ float red[4];
    int tid = threadIdx.x;
    if (blockIdx.x == 0 && tid == 0) counter[0] = 0;   // reset for k_comb

    for (int idx = tid; idx < 2048; idx += 256) {
        int h = idx >> 3, s = idx & 7;
        float v = 0.f;
        if (s < 4) v = Wenc[s * H_ + h];
        else if (s == 4) v = benc[h];
        ldsWpack[idx] = v;
    }
    for (int idx = tid; idx < 4096; idx += 256) {
        int h = idx >> 4, c = idx & 15;
        ldsWemit[idx] = (c < C_) ? Wemit[h * C_ + c] : 0.f;
    }
    __syncthreads();

    int wid = tid >> 6, lane = tid & 63;
    int g = lane >> 4, li = lane & 15;
    int b0 = blockIdx.x >> 5;                     // 32 blocks per batch
    int tb0 = (blockIdx.x & 31) * 256 + wid * 64; // wave covers 64 rows
    size_t grow0 = (size_t)b0 * T_ + tb0;

    float4 xs[4];
#pragma unroll
    for (int tt = 0; tt < 4; tt++)
        xs[tt] = *(const float4*)(seq + (grow0 + tt * 16 + li) * 4);

    f32x4 acc[4];
#pragma unroll
    for (int tt = 0; tt < 4; tt++) acc[tt] = (f32x4){0.f, 0.f, 0.f, 0.f};

#pragma unroll 1
    for (int kb = 0; kb < 8; kb++) {
        float We[8][5], wm[8];
#pragma unroll
        for (int e = 0; e < 8; e++) {
            int h = 32 * kb + 4 * g + (e & 3) + 16 * (e >> 2);
            float4 w4 = *(const float4*)&ldsWpack[h * 8];
            We[e][0] = w4.x; We[e][1] = w4.y; We[e][2] = w4.z; We[e][3] = w4.w;
            We[e][4] = ldsWpack[h * 8 + 4];
            wm[e] = ldsWemit[h * 16 + li];
        }
        unsigned a0, a1, a2, a3;
        asm("v_cvt_pk_bf16_f32 %0, %1, %2" : "=v"(a0) : "v"(wm[0]), "v"(wm[1]));
        asm("v_cvt_pk_bf16_f32 %0, %1, %2" : "=v"(a1) : "v"(wm[2]), "v"(wm[3]));
        asm("v_cvt_pk_bf16_f32 %0, %1, %2" : "=v"(a2) : "v"(wm[4]), "v"(wm[5]));
        asm("v_cvt_pk_bf16_f32 %0, %1, %2" : "=v"(a3) : "v"(wm[6]), "v"(wm[7]));
        union { short8 s8; uint4 u4; } au;
        au.u4 = make_uint4(a0, a1, a2, a3);

#pragma unroll
        for (int tt = 0; tt < 4; tt++) {
            float4 x = xs[tt];
            float hv[8];
#pragma unroll
            for (int e = 0; e < 8; e++) {
                float h = fmaf(x.x, We[e][0],
                          fmaf(x.y, We[e][1],
                          fmaf(x.z, We[e][2],
                          fmaf(x.w, We[e][3], We[e][4]))));
                hv[e] = fmaxf(h, 0.f);
            }
            unsigned u0, u1, u2, u3;
            asm("v_cvt_pk_bf16_f32 %0, %1, %2" : "=v"(u0) : "v"(hv[0]), "v"(hv[1]));
            asm("v_cvt_pk_bf16_f32 %0, %1, %2" : "=v"(u1) : "v"(hv[2]), "v"(hv[3]));
            asm("v_cvt_pk_bf16_f32 %0, %1, %2" : "=v"(u2) : "v"(hv[4]), "v"(hv[5]));
            asm("v_cvt_pk_bf16_f32 %0, %1, %2" : "=v"(u3) : "v"(hv[6]), "v"(hv[7]));
            union { short8 s8; uint4 u4; } bfu;
            bfu.u4 = make_uint4(u0, u1, u2, u3);
            acc[tt] = __builtin_amdgcn_mfma_f32_16x16x32_bf16(au.s8, bfu.s8, acc[tt], 0, 0, 0);
        }
    }

    int len = lengths[b0];
    const int* lab = labels + (size_t)b0 * T_;
    float bm[4];
#pragma unroll
    for (int r = 0; r < 4; r++) {
        int c = 4 * g + r;
        bm[r] = (c < C_) ? bemit[c] : 0.f;
    }

    float nacc = 0.f;
#pragma unroll
    for (int tt = 0; tt < 4; tt++) {
        float em0 = acc[tt].x + bm[0];
        float em1 = acc[tt].y + bm[1];
        float em2 = acc[tt].z + bm[2];
        float em3 = acc[tt].w + bm[3];

        int t = tb0 + tt * 16 + li;
        int tg = lab[t]; tg = tg < 0 ? 0 : tg;
        if (g == (tg >> 2) && t < len) {
            int r = tg & 3;
            float emtg = r == 0 ? em0 : r == 1 ? em1 : r == 2 ? em2 : em3;
            float contrib;
            if (t == 0) {
                contrib = startt[tg] + emtg;
            } else {
                int tp = lab[t - 1]; tp = tp < 0 ? 0 : tp;
                contrib = trans[tp * C_ + tg] + emtg;
            }
            if (t == len - 1) contrib += endt[tg];
            nacc += contrib;
        }

        if (g < 3) {
            float e0 = __expf(em0), e1 = __expf(em1);
            float e2 = __expf(em2), e3 = __expf(em3);
            unsigned u0, u1;
            asm("v_cvt_pk_bf16_f32 %0, %1, %2" : "=v"(u0) : "v"(e0), "v"(e1));
            asm("v_cvt_pk_bf16_f32 %0, %1, %2" : "=v"(u1) : "v"(e2), "v"(e3));
            *(uint2*)(expem + (grow0 + tt * 16 + li) * 16 + g * 4) = make_uint2(u0, u1);
        }
    }

#pragma unroll
    for (int off = 32; off > 0; off >>= 1) nacc += __shfl_down(nacc, off);
    if (lane == 0) red[wid] = nacc;
    __syncthreads();
    if (tid == 0) numpart[blockIdx.x] = red[0] + red[1] + red[2] + red[3];
}

// ---------------------------------------------------------------------------
// scale-folded pair combine, one row i: D_row_i = normalize(A_i . diag(w) . B)
// EXACT math of the r10 k_comb inner task (association order preserved).
// Reads A row i + whole B; writes D row i (D may alias A: tasks touch only
// their own row).
// ---------------------------------------------------------------------------
__device__ __forceinline__ void combineRow(const float* __restrict__ A,
                                           const float* __restrict__ Bm,
                                           float* __restrict__ D, int i)
{
    float a[C_];
#pragma unroll
    for (int kk = 0; kk < C_; kk++) a[kk] = A[i * 12 + kk];
    float als = A[i * 12 + 11];
    float m = Bm[11];
#pragma unroll
    for (int kk = 1; kk < C_; kk++) m = fmaxf(m, Bm[kk * 12 + 11]);
    float wv[C_];
#pragma unroll
    for (int kk = 0; kk < C_; kk++)
        wv[kk] = a[kk] * __expf(Bm[kk * 12 + 11] - m);
    float outv[C_];
#pragma unroll
    for (int j = 0; j < C_; j++) outv[j] = wv[0] * Bm[j];
#pragma unroll
    for (int kk = 1; kk < C_; kk++)
#pragma unroll
        for (int j = 0; j < C_; j++)
            outv[j] = fmaf(wv[kk], Bm[kk * 12 + j], outv[j]);
    float s = 0.f;
#pragma unroll
    for (int j = 0; j < C_; j++) s += outv[j];
    float rr = 1.f / s;
#pragma unroll
    for (int j = 0; j < C_; j++) D[i * 12 + j] = outv[j] * rr;
    D[i * 12 + 11] = als + m + __logf(s);
}

// ---------------------------------------------------------------------------
// K2: MFMA chunk scan + in-block 4->1 pre-combine.
// Wave = 1 chunk (P=G^T in registers, fixed eT^T A-frag — r10 scheme).
// FIX vs r10: fully-unrolled su loop, statically-indexed prefetch buffers,
// NO register rotation => no s_waitcnt vmcnt(0) drain per group. Groups 0-3
// preloaded before the exp prologue; group g+4 issued at top of group g
// (distance ~4 groups > L3/HBM latency).
// Then: 4 waves exchange P via 3KB LDS and run 2 binary-combine levels
// (identical association order to the old 8-level tree) -> 64 leaves/batch.
// ---------------------------------------------------------------------------
__global__ __launch_bounds__(256, 4) void k_chunks(
    const float* __restrict__ trans, const int* __restrict__ lengths,
    const unsigned short* __restrict__ expem, float* __restrict__ G)
{
    __shared__ float Mb[4][192];      // [wave][i*12+j]
    int tid = threadIdx.x;
    int wave = tid >> 6, lane = tid & 63;
    int i = lane & 15, g = lane >> 4;

    int bk = blockIdx.x;              // 1024 blocks; 64 per batch
    int b = bk >> 6;
    int k = ((bk & 63) << 2) | wave;  // chunk index in batch, 0..255
    int t0 = 1 + k * LCH;
    int len = lengths[b];
    int tl = t0 + LCH; if (len < tl) tl = len;   // active steps: t in [t0, tl)
    int nact = tl - t0;                          // may be <= 0

    const unsigned short* emp = expem + ((size_t)b * T_ + t0) * 16 + 4 * g;

    // prefetch groups 0..3 (16 rows) before the transcendental prologue
    uint2 R[8][4];
#pragma unroll
    for (int q = 0; q < 16; q++)
        R[q >> 2][q & 3] = *(const uint2*)(emp + (size_t)q * 16);

    // A-frag: A[m=i][k=4g+e] = exp(trans[k*C+i]), zero-padded
    float af[4];
#pragma unroll
    for (int e = 0; e < 4; e++) {
        int kk = 4 * g + e;
        af[e] = (i < C_ && kk < C_) ? __expf(trans[kk * C_ + i]) : 0.f;
    }
    unsigned a0, a1;
    asm("v_cvt_pk_bf16_f32 %0, %1, %2" : "=v"(a0) : "v"(af[0]), "v"(af[1]));
    asm("v_cvt_pk_bf16_f32 %0, %1, %2" : "=v"(a1) : "v"(af[2]), "v"(af[3]));
    union { short8 s8; uint4 u4; } A; A.u4 = make_uint4(a0, a1, 0u, 0u);

    // P = identity (column i per lane; junk columns i>=11 never escape)
    float p0 = (4 * g + 0 == i) ? 1.f : 0.f;
    float p1 = (4 * g + 1 == i) ? 1.f : 0.f;
    float p2 = (4 * g + 2 == i) ? 1.f : 0.f;
    float p3 = (4 * g + 3 == i) ? 1.f : 0.f;
    float ls = 0.f;

#pragma unroll
    for (int su = 0; su < 8; su++) {
        if (su < 4) {                  // issue group su+4 loads (static regs)
#pragma unroll
            for (int q = 0; q < 4; q++)
                R[su + 4][q] = *(const uint2*)(emp + (size_t)((su + 4) * 4 + q) * 16);
        }
#pragma unroll
        for (int ss = 0; ss < 4; ss++) {
            if (su * 4 + ss < nact) {  // wave-uniform
                unsigned b0u, b1u;
                asm("v_cvt_pk_bf16_f32 %0, %1, %2" : "=v"(b0u) : "v"(p0), "v"(p1));
                asm("v_cvt_pk_bf16_f32 %0, %1, %2" : "=v"(b1u) : "v"(p2), "v"(p3));
                union { short8 s8; uint4 u4; } Bf; Bf.u4 = make_uint4(b0u, b1u, 0u, 0u);
                f32x4 acc = __builtin_amdgcn_mfma_f32_16x16x32_bf16(
                    A.s8, Bf.s8, (f32x4){0.f, 0.f, 0.f, 0.f}, 0, 0, 0);
                uint2 emu = R[su][ss];
                p0 = acc.x * __uint_as_float(emu.x << 16);
                p1 = acc.y * __uint_as_float(emu.x & 0xffff0000u);
                p2 = acc.z * __uint_as_float(emu.y << 16);
                p3 = acc.w * __uint_as_float(emu.y & 0xffff0000u);
            }
        }
        // column rescale (lanes i,16+i,32+i,48+i = column i)
        float part = (p0 + p1) + (p2 + p3);
        part += __shfl_xor(part, 16);
        part += __shfl_xor(part, 32);
        float r = 1.f / part;
        p0 *= r; p1 *= r; p2 *= r; p3 *= r;
        ls += __logf(part);
    }

    // ---- stage P into LDS (row-major G: Mb[w][i*12+j], ls at j=11) ----
    if (i < C_ && g < 3) {
        float w3 = (g == 2) ? ls : p3;
        *(float4*)&Mb[wave][i * 12 + 4 * g] = make_float4(p0, p1, p2, w3);
    }
    __syncthreads();

    // level 1: (0,1)->slot0 by wave0, (2,3)->slot2 by wave2
    if ((wave == 0 || wave == 2) && lane < C_)
        combineRow(Mb[wave], Mb[wave + 1], Mb[wave], lane);
    __syncthreads();

    // level 2: (slot0, slot2) -> leaf, straight to global from registers
    if (wave == 0 && lane < C_) {
        float out[12];
        {
            const float* Aa = Mb[0]; const float* Bm = Mb[2];
            float a[C_];
#pragma unroll
            for (int kk = 0; kk < C_; kk++) a[kk] = Aa[lane * 12 + kk];
            float als = Aa[lane * 12 + 11];
            float m = Bm[11];
#pragma unroll
            for (int kk = 1; kk < C_; kk++) m = fmaxf(m, Bm[kk * 12 + 11]);
            float wv[C_];
#pragma unroll
            for (int kk = 0; kk < C_; kk++)
                wv[kk] = a[kk] * __expf(Bm[kk * 12 + 11] - m);
            float outv[C_];
#pragma unroll
            for (int j = 0; j < C_; j++) outv[j] = wv[0] * Bm[j];
#pragma unroll
            for (int kk = 1; kk < C_; kk++)
#pragma unroll
                for (int j = 0; j < C_; j++)
                    outv[j] = fmaf(wv[kk], Bm[kk * 12 + j], outv[j]);
            float s = 0.f;
#pragma unroll
            for (int j = 0; j < C_; j++) s += outv[j];
            float rr = 1.f / s;
#pragma unroll
            for (int j = 0; j < C_; j++) out[j] = outv[j] * rr;
            out[11] = als + m + __logf(s);
        }
        float* o = G + ((size_t)b * KL + (bk & 63)) * 132 + lane * 12;
        *(float4*)(o + 0) = make_float4(out[0], out[1], out[2], out[3]);
        *(float4*)(o + 4) = make_float4(out[4], out[5], out[6], out[7]);
        *(float4*)(o + 8) = make_float4(out[8], out[9], out[10], out[11]);
    }
}

// ---------------------------------------------------------------------------
// K3: per-batch LDS tree combine (64 leaves, 6 levels, 34KB LDS) + den +
// fused final reduction (last-block atomic pattern).
// ---------------------------------------------------------------------------
__global__ __launch_bounds__(512, 1) void k_comb(
    const float* __restrict__ startt, const float* __restrict__ endt,
    const unsigned short* __restrict__ expem, const float* __restrict__ G0,
    const float* __restrict__ numpart, float* __restrict__ dens,
    unsigned* __restrict__ counter, float* __restrict__ out)
{
    __shared__ float M[KL * 132];      // 33792 bytes
    int b = blockIdx.x, tid = threadIdx.x;

    float numb = 0.f;
    if (tid < 64) {
        float v = (tid < 32) ? numpart[b * 32 + tid] : 0.f;
#pragma unroll
        for (int off = 32; off > 0; off >>= 1) v += __shfl_down(v, off);
        numb = v;                       // valid on tid 0
    }

    const float4* src = (const float4*)(G0 + (size_t)b * KL * 132);
    float4* dst = (float4*)M;
#pragma unroll 4
    for (int idx = tid; idx < KL * 132 / 4; idx += 512) dst[idx] = src[idx];
    __syncthreads();

    for (int stride = 1; stride < KL; stride <<= 1) {
        int npair = KL / (2 * stride);
        for (int task = tid; task < npair * C_; task += 512) {
            int p = task / C_, i = task - p * C_;
            float* A  = M + (size_t)(2 * stride * p) * 132;
            float* Bm = M + (size_t)(2 * stride * p + stride) * 132;
            combineRow(A, Bm, A, i);
        }
        __syncthreads();
    }

    if (tid == 0) {
        const float* Cm = M;
        const unsigned short* em0 = expem + (size_t)b * T_ * 16;
        float av[C_];
        float mm = -1e30f;
#pragma unroll
        for (int i2 = 0; i2 < C_; i2++) {
            float e0 = __uint_as_float((unsigned)em0[i2] << 16);
            av[i2] = startt[i2] + __logf(e0) + Cm[i2 * 12 + 11];
            mm = fmaxf(mm, av[i2]);
        }
        float S[C_];
#pragma unroll
        for (int j = 0; j < C_; j++) S[j] = 0.f;
#pragma unroll
        for (int i2 = 0; i2 < C_; i2++) {
            float e = __expf(av[i2] - mm);
#pragma unroll
            for (int j = 0; j < C_; j++) S[j] = fmaf(e, Cm[i2 * 12 + j], S[j]);
        }
        float tot = 0.f;
#pragma unroll
        for (int j = 0; j < C_; j++) tot += S[j] * __expf(endt[j]);
        float den = __logf(tot) + mm;

        float loss = numb - den;
        __hip_atomic_store(&dens[b], loss, __ATOMIC_RELEASE, __HIP_MEMORY_SCOPE_AGENT);
        unsigned old = __hip_atomic_fetch_add(counter, 1u, __ATOMIC_ACQ_REL,
                                              __HIP_MEMORY_SCOPE_AGENT);
        if (old == B_ - 1) {            // last block: fixed-order sum (deterministic)
            float s = 0.f;
#pragma unroll
            for (int j = 0; j < B_; j++)
                s += __hip_atomic_load(&dens[j], __ATOMIC_ACQUIRE,
                                       __HIP_MEMORY_SCOPE_AGENT);
            out[0] = -s / (float)B_;
        }
    }
}

extern "C" void kernel_launch(void* const* d_in, const int* in_sizes, int n_in,
                              void* d_out, int out_size, void* d_ws, size_t ws_size,
                              hipStream_t stream) {
    const float* seq    = (const float*)d_in[0];
    const float* Wenc   = (const float*)d_in[1];
    const float* benc   = (const float*)d_in[2];
    const float* Wemit  = (const float*)d_in[3];
    const float* bemit  = (const float*)d_in[4];
    const float* startt = (const float*)d_in[5];
    const float* trans  = (const float*)d_in[6];
    const float* endt   = (const float*)d_in[7];
    const int*   lengths= (const int*)d_in[8];
    const int*   labels = (const int*)d_in[9];

    char* w = (char*)d_ws;
    unsigned short* expem  = (unsigned short*)w;            // B*T*16 bf16 = 4,194,304 B
    float*          G0     = (float*)(w + 4194304);         // 1024*132 f32 = 540,672 B
    float*          numpart= (float*)(w + 4734976);         // 512 f32
    float*          dens   = (float*)(w + 4737024);         // 16 f32
    unsigned*       counter= (unsigned*)(w + 4737088);      // 1 u32
    float*          out    = (float*)d_out;

    k_em<<<512, 256, 0, stream>>>(seq, Wenc, benc, Wemit, bemit, trans,
                                  startt, endt, lengths, labels,
                                  expem, numpart, counter);
    k_chunks<<<1024, 256, 0, stream>>>(trans, lengths, expem, G0);
    k_comb<<<B_, 512, 0, stream>>>(startt, endt, expem, G0, numpart,
                                   dens, counter, out);
}

// Round 12
// 39.028 us; speedup vs baseline: 1.6180x; 1.1589x over previous
//
#include <hip/hip_runtime.h>
#include <hip/hip_bf16.h>

#define B_   16
#define T_   8192
#define H_   256
#define C_   11
#define KL   32             // leaves per batch (one per fused block)

typedef __attribute__((ext_vector_type(8))) short short8;
typedef __attribute__((ext_vector_type(4))) float f32x4;

// ---------------------------------------------------------------------------
// scale-folded pair combine, one row i: D_row_i = normalize(A_i . diag(w) . B)
// (exact math/association of the r10/r11 combine)
// ---------------------------------------------------------------------------
__device__ __forceinline__ void combineRow(const float* __restrict__ A,
                                           const float* __restrict__ Bm,
                                           float* __restrict__ D, int i)
{
    float a[C_];
#pragma unroll
    for (int kk = 0; kk < C_; kk++) a[kk] = A[i * 12 + kk];
    float als = A[i * 12 + 11];
    float m = Bm[11];
#pragma unroll
    for (int kk = 1; kk < C_; kk++) m = fmaxf(m, Bm[kk * 12 + 11]);
    float wv[C_];
#pragma unroll
    for (int kk = 0; kk < C_; kk++)
        wv[kk] = a[kk] * __expf(Bm[kk * 12 + 11] - m);
    float outv[C_];
#pragma unroll
    for (int j = 0; j < C_; j++) outv[j] = wv[0] * Bm[j];
#pragma unroll
    for (int kk = 1; kk < C_; kk++)
#pragma unroll
        for (int j = 0; j < C_; j++)
            outv[j] = fmaf(wv[kk], Bm[kk * 12 + j], outv[j]);
    float s = 0.f;
#pragma unroll
    for (int j = 0; j < C_; j++) s += outv[j];
    float rr = 1.f / s;
#pragma unroll
    for (int j = 0; j < C_; j++) D[i * 12 + j] = outv[j] * rr;
    D[i * 12 + 11] = als + m + __logf(s);
}

// ---------------------------------------------------------------------------
// K1 FUSED: encoder MFMA + emissions + numerator + CHUNK SCAN + 4->1 combine.
// Block = 256 consecutive rows of one batch. em never touches global memory:
// exp(em) bf16 staged in LDS (each wave writes & scans ITS OWN 64 rows).
// Scan: P=G^T in registers, A=eT^T fixed frag, 64 MFMA steps from LDS,
// rescale every 4 (r10-verified layout). Then r11's LDS tree 4 waves -> 1
// leaf => 32 leaves/batch.
// ---------------------------------------------------------------------------
__global__ __launch_bounds__(256) void k_fused(
    const float* __restrict__ seq, const float* __restrict__ Wenc,
    const float* __restrict__ benc, const float* __restrict__ Wemit,
    const float* __restrict__ bemit, const float* __restrict__ trans,
    const float* __restrict__ startt, const float* __restrict__ endt,
    const int* __restrict__ lengths, const int* __restrict__ labels,
    float* __restrict__ G, float* __restrict__ numpart,
    float* __restrict__ em0f, unsigned* __restrict__ counter)
{
    __shared__ float ldsWpack[2048];   // [256][8]: w0..w3, benc, pad
    __shared__ float ldsWemit[4096];   // [256][16]: Wemit padded
    __shared__ unsigned emLds[256 * 8];// [row][8] uints: bf16x2 em slots 0..5, 6..7 zeroed
    __shared__ float Mb[4][192];       // per-wave P for the 4->1 combine
    __shared__ float red[4];

    int tid = threadIdx.x;
    if (blockIdx.x == 0 && tid == 0) counter[0] = 0;   // reset for k_comb

    for (int idx = tid; idx < 2048; idx += 256) {
        int h = idx >> 3, s = idx & 7;
        float v = 0.f;
        if (s < 4) v = Wenc[s * H_ + h];
        else if (s == 4) v = benc[h];
        ldsWpack[idx] = v;
    }
    for (int idx = tid; idx < 4096; idx += 256) {
        int h = idx >> 4, c = idx & 15;
        ldsWemit[idx] = (c < C_) ? Wemit[h * C_ + c] : 0.f;
    }
    __syncthreads();

    int wid = tid >> 6, lane = tid & 63;
    int g = lane >> 4, li = lane & 15;
    int b0 = blockIdx.x >> 5;                 // 32 blocks per batch
    int kb31 = blockIdx.x & 31;
    int base = kb31 * 256;                    // in-batch row base of block
    int tb0 = base + wid * 64;                // wave covers rows [tb0, tb0+64)
    size_t grow0 = (size_t)b0 * T_ + tb0;

    // ======================= encoder (r7-verified) =========================
    float4 xs[4];
#pragma unroll
    for (int tt = 0; tt < 4; tt++)
        xs[tt] = *(const float4*)(seq + (grow0 + tt * 16 + li) * 4);

    f32x4 acc[4];
#pragma unroll
    for (int tt = 0; tt < 4; tt++) acc[tt] = (f32x4){0.f, 0.f, 0.f, 0.f};

#pragma unroll 1
    for (int kb = 0; kb < 8; kb++) {
        float We[8][5], wm[8];
#pragma unroll
        for (int e = 0; e < 8; e++) {
            int h = 32 * kb + 4 * g + (e & 3) + 16 * (e >> 2);
            float4 w4 = *(const float4*)&ldsWpack[h * 8];
            We[e][0] = w4.x; We[e][1] = w4.y; We[e][2] = w4.z; We[e][3] = w4.w;
            We[e][4] = ldsWpack[h * 8 + 4];
            wm[e] = ldsWemit[h * 16 + li];
        }
        unsigned a0, a1, a2, a3;
        asm("v_cvt_pk_bf16_f32 %0, %1, %2" : "=v"(a0) : "v"(wm[0]), "v"(wm[1]));
        asm("v_cvt_pk_bf16_f32 %0, %1, %2" : "=v"(a1) : "v"(wm[2]), "v"(wm[3]));
        asm("v_cvt_pk_bf16_f32 %0, %1, %2" : "=v"(a2) : "v"(wm[4]), "v"(wm[5]));
        asm("v_cvt_pk_bf16_f32 %0, %1, %2" : "=v"(a3) : "v"(wm[6]), "v"(wm[7]));
        union { short8 s8; uint4 u4; } au;
        au.u4 = make_uint4(a0, a1, a2, a3);

#pragma unroll
        for (int tt = 0; tt < 4; tt++) {
            float4 x = xs[tt];
            float hv[8];
#pragma unroll
            for (int e = 0; e < 8; e++) {
                float h = fmaf(x.x, We[e][0],
                          fmaf(x.y, We[e][1],
                          fmaf(x.z, We[e][2],
                          fmaf(x.w, We[e][3], We[e][4]))));
                hv[e] = fmaxf(h, 0.f);
            }
            unsigned u0, u1, u2, u3;
            asm("v_cvt_pk_bf16_f32 %0, %1, %2" : "=v"(u0) : "v"(hv[0]), "v"(hv[1]));
            asm("v_cvt_pk_bf16_f32 %0, %1, %2" : "=v"(u1) : "v"(hv[2]), "v"(hv[3]));
            asm("v_cvt_pk_bf16_f32 %0, %1, %2" : "=v"(u2) : "v"(hv[4]), "v"(hv[5]));
            asm("v_cvt_pk_bf16_f32 %0, %1, %2" : "=v"(u3) : "v"(hv[6]), "v"(hv[7]));
            union { short8 s8; uint4 u4; } bfu;
            bfu.u4 = make_uint4(u0, u1, u2, u3);
            acc[tt] = __builtin_amdgcn_mfma_f32_16x16x32_bf16(au.s8, bfu.s8, acc[tt], 0, 0, 0);
        }
    }

    // ============== epilogue: numerator + exp + LDS em store ===============
    int len = lengths[b0];
    const int* lab = labels + (size_t)b0 * T_;
    float bm[4];
#pragma unroll
    for (int r = 0; r < 4; r++) {
        int c = 4 * g + r;
        bm[r] = (c < C_) ? bemit[c] : 0.f;
    }

    float nacc = 0.f;
#pragma unroll
    for (int tt = 0; tt < 4; tt++) {
        float em0 = acc[tt].x + bm[0];
        float em1 = acc[tt].y + bm[1];
        float em2 = acc[tt].z + bm[2];
        float em3 = acc[tt].w + bm[3];

        int t = tb0 + tt * 16 + li;            // in-batch row
        int tg = lab[t]; tg = tg < 0 ? 0 : tg;
        if (g == (tg >> 2) && t < len) {
            int r = tg & 3;
            float emtg = r == 0 ? em0 : r == 1 ? em1 : r == 2 ? em2 : em3;
            float contrib;
            if (t == 0) {
                contrib = startt[tg] + emtg;
            } else {
                int tp = lab[t - 1]; tp = tp < 0 ? 0 : tp;
                contrib = trans[tp * C_ + tg] + emtg;
            }
            if (t == len - 1) contrib += endt[tg];
            nacc += contrib;
        }

        int row = wid * 64 + tt * 16 + li;     // block-local row
        if (g < 3) {
            float e0 = __expf(em0), e1 = __expf(em1);
            float e2 = __expf(em2), e3 = __expf(em3);
            unsigned u0, u1;
            asm("v_cvt_pk_bf16_f32 %0, %1, %2" : "=v"(u0) : "v"(e0), "v"(e1));
            asm("v_cvt_pk_bf16_f32 %0, %1, %2" : "=v"(u1) : "v"(e2), "v"(e3));
            emLds[row * 8 + 2 * g]     = u0;
            emLds[row * 8 + 2 * g + 1] = u1;
            if (kb31 == 0 && row == 0) {       // em row 0 -> side buffer (f32 of bf16)
                float* o0 = em0f + b0 * 12 + 4 * g;
                o0[0] = __uint_as_float(u0 << 16);
                o0[1] = __uint_as_float(u0 & 0xffff0000u);
                o0[2] = __uint_as_float(u1 << 16);
                o0[3] = __uint_as_float(u1 & 0xffff0000u);
            }
        } else {                                // zero junk slots 6,7 (no NaN feed)
            emLds[row * 8 + 6] = 0u;
            emLds[row * 8 + 7] = 0u;
        }
    }

#pragma unroll
    for (int off = 32; off > 0; off >>= 1) nacc += __shfl_down(nacc, off);
    if (lane == 0) red[wid] = nacc;
    __syncthreads();
    if (tid == 0) numpart[blockIdx.x] = red[0] + red[1] + red[2] + red[3];

    // ===================== chunk scan (64 steps, LDS-fed) ==================
    // wave w scans its OWN rows [tb0, tb0+64) — no barrier needed (same-wave
    // LDS RAW handled by lgkmcnt).
    const unsigned* erow = &emLds[wid * 64 * 8 + 2 * g];

    uint2 EA[4], EB[4];
#pragma unroll
    for (int q = 0; q < 4; q++) EA[q] = *(const uint2*)(erow + q * 8);

    float af[4];
#pragma unroll
    for (int e = 0; e < 4; e++) {
        int kk = 4 * g + e;
        af[e] = (li < C_ && kk < C_) ? __expf(trans[kk * C_ + li]) : 0.f;
    }
    unsigned fa0, fa1;
    asm("v_cvt_pk_bf16_f32 %0, %1, %2" : "=v"(fa0) : "v"(af[0]), "v"(af[1]));
    asm("v_cvt_pk_bf16_f32 %0, %1, %2" : "=v"(fa1) : "v"(af[2]), "v"(af[3]));
    union { short8 s8; uint4 u4; } A; A.u4 = make_uint4(fa0, fa1, 0u, 0u);

    float p0 = (4 * g + 0 == li) ? 1.f : 0.f;
    float p1 = (4 * g + 1 == li) ? 1.f : 0.f;
    float p2 = (4 * g + 2 == li) ? 1.f : 0.f;
    float p3 = (4 * g + 3 == li) ? 1.f : 0.f;
    float ls = 0.f;

#pragma unroll
    for (int grp = 0; grp < 16; grp++) {
        if (grp < 15) {                        // prefetch next group (static regs)
            if ((grp & 1) == 0) {
#pragma unroll
                for (int q = 0; q < 4; q++)
                    EB[q] = *(const uint2*)(erow + ((grp + 1) * 4 + q) * 8);
            } else {
#pragma unroll
                for (int q = 0; q < 4; q++)
                    EA[q] = *(const uint2*)(erow + ((grp + 1) * 4 + q) * 8);
            }
        }
#pragma unroll
        for (int ss = 0; ss < 4; ss++) {
            int t = base + wid * 64 + grp * 4 + ss;   // in-batch step index
            if (t >= 1 && t < len) {                  // wave-uniform
                unsigned b0u, b1u;
                asm("v_cvt_pk_bf16_f32 %0, %1, %2" : "=v"(b0u) : "v"(p0), "v"(p1));
                asm("v_cvt_pk_bf16_f32 %0, %1, %2" : "=v"(b1u) : "v"(p2), "v"(p3));
                union { short8 s8; uint4 u4; } Bf; Bf.u4 = make_uint4(b0u, b1u, 0u, 0u);
                f32x4 pa = __builtin_amdgcn_mfma_f32_16x16x32_bf16(
                    A.s8, Bf.s8, (f32x4){0.f, 0.f, 0.f, 0.f}, 0, 0, 0);
                uint2 emu = ((grp & 1) == 0) ? EA[ss] : EB[ss];
                p0 = pa.x * __uint_as_float(emu.x << 16);
                p1 = pa.y * __uint_as_float(emu.x & 0xffff0000u);
                p2 = pa.z * __uint_as_float(emu.y << 16);
                p3 = pa.w * __uint_as_float(emu.y & 0xffff0000u);
            }
        }
        float part = (p0 + p1) + (p2 + p3);    // column i sum
        part += __shfl_xor(part, 16);
        part += __shfl_xor(part, 32);
        float r = 1.f / part;
        p0 *= r; p1 *= r; p2 *= r; p3 *= r;
        ls += __logf(part);
    }

    // ================= 4 waves -> 1 leaf (r11 combine) =====================
    if (li < C_ && g < 3) {
        float w3 = (g == 2) ? ls : p3;
        *(float4*)&Mb[wid][li * 12 + 4 * g] = make_float4(p0, p1, p2, w3);
    }
    __syncthreads();

    if ((wid == 0 || wid == 2) && lane < C_)
        combineRow(Mb[wid], Mb[wid + 1], Mb[wid], lane);
    __syncthreads();

    if (wid == 0 && lane < C_) {
        float out[12];
        {
            const float* Aa = Mb[0]; const float* Bm = Mb[2];
            float a[C_];
#pragma unroll
            for (int kk = 0; kk < C_; kk++) a[kk] = Aa[lane * 12 + kk];
            float als = Aa[lane * 12 + 11];
            float m = Bm[11];
#pragma unroll
            for (int kk = 1; kk < C_; kk++) m = fmaxf(m, Bm[kk * 12 + 11]);
            float wv[C_];
#pragma unroll
            for (int kk = 0; kk < C_; kk++)
                wv[kk] = a[kk] * __expf(Bm[kk * 12 + 11] - m);
            float outv[C_];
#pragma unroll
            for (int j = 0; j < C_; j++) outv[j] = wv[0] * Bm[j];
#pragma unroll
            for (int kk = 1; kk < C_; kk++)
#pragma unroll
                for (int j = 0; j < C_; j++)
                    outv[j] = fmaf(wv[kk], Bm[kk * 12 + j], outv[j]);
            float s = 0.f;
#pragma unroll
            for (int j = 0; j < C_; j++) s += outv[j];
            float rr = 1.f / s;
#pragma unroll
            for (int j = 0; j < C_; j++) out[j] = outv[j] * rr;
            out[11] = als + m + __logf(s);
        }
        float* o = G + ((size_t)b0 * KL + kb31) * 132 + lane * 12;
        *(float4*)(o + 0) = make_float4(out[0], out[1], out[2], out[3]);
        *(float4*)(o + 4) = make_float4(out[4], out[5], out[6], out[7]);
        *(float4*)(o + 8) = make_float4(out[8], out[9], out[10], out[11]);
    }
}

// ---------------------------------------------------------------------------
// K3: per-batch LDS tree combine (32 leaves, 5 levels, 17KB LDS) + den +
// fused final reduction (last-block atomic pattern).
// ---------------------------------------------------------------------------
__global__ __launch_bounds__(512, 1) void k_comb(
    const float* __restrict__ startt, const float* __restrict__ endt,
    const float* __restrict__ em0f, const float* __restrict__ G0,
    const float* __restrict__ numpart, float* __restrict__ dens,
    unsigned* __restrict__ counter, float* __restrict__ out)
{
    __shared__ float M[KL * 132];      // 16896 bytes
    int b = blockIdx.x, tid = threadIdx.x;

    float numb = 0.f;
    if (tid < 64) {
        float v = (tid < 32) ? numpart[b * 32 + tid] : 0.f;
#pragma unroll
        for (int off = 32; off > 0; off >>= 1) v += __shfl_down(v, off);
        numb = v;                       // valid on tid 0
    }

    const float4* src = (const float4*)(G0 + (size_t)b * KL * 132);
    float4* dst = (float4*)M;
#pragma unroll 2
    for (int idx = tid; idx < KL * 132 / 4; idx += 512) dst[idx] = src[idx];
    __syncthreads();

    for (int stride = 1; stride < KL; stride <<= 1) {
        int npair = KL / (2 * stride);
        for (int task = tid; task < npair * C_; task += 512) {
            int p = task / C_, i = task - p * C_;
            float* A  = M + (size_t)(2 * stride * p) * 132;
            float* Bm = M + (size_t)(2 * stride * p + stride) * 132;
            combineRow(A, Bm, A, i);
        }
        __syncthreads();
    }

    if (tid == 0) {
        const float* Cm = M;
        const float* e0 = em0f + b * 12;
        float av[C_];
        float mm = -1e30f;
#pragma unroll
        for (int i2 = 0; i2 < C_; i2++) {
            av[i2] = startt[i2] + __logf(e0[i2]) + Cm[i2 * 12 + 11];
            mm = fmaxf(mm, av[i2]);
        }
        float S[C_];
#pragma unroll
        for (int j = 0; j < C_; j++) S[j] = 0.f;
#pragma unroll
        for (int i2 = 0; i2 < C_; i2++) {
            float e = __expf(av[i2] - mm);
#pragma unroll
            for (int j = 0; j < C_; j++) S[j] = fmaf(e, Cm[i2 * 12 + j], S[j]);
        }
        float tot = 0.f;
#pragma unroll
        for (int j = 0; j < C_; j++) tot += S[j] * __expf(endt[j]);
        float den = __logf(tot) + mm;

        float loss = numb - den;
        __hip_atomic_store(&dens[b], loss, __ATOMIC_RELEASE, __HIP_MEMORY_SCOPE_AGENT);
        unsigned old = __hip_atomic_fetch_add(counter, 1u, __ATOMIC_ACQ_REL,
                                              __HIP_MEMORY_SCOPE_AGENT);
        if (old == B_ - 1) {            // last block: fixed-order sum (deterministic)
            float s = 0.f;
#pragma unroll
            for (int j = 0; j < B_; j++)
                s += __hip_atomic_load(&dens[j], __ATOMIC_ACQUIRE,
                                       __HIP_MEMORY_SCOPE_AGENT);
            out[0] = -s / (float)B_;
        }
    }
}

extern "C" void kernel_launch(void* const* d_in, const int* in_sizes, int n_in,
                              void* d_out, int out_size, void* d_ws, size_t ws_size,
                              hipStream_t stream) {
    const float* seq    = (const float*)d_in[0];
    const float* Wenc   = (const float*)d_in[1];
    const float* benc   = (const float*)d_in[2];
    const float* Wemit  = (const float*)d_in[3];
    const float* bemit  = (const float*)d_in[4];
    const float* startt = (const float*)d_in[5];
    const float* trans  = (const float*)d_in[6];
    const float* endt   = (const float*)d_in[7];
    const int*   lengths= (const int*)d_in[8];
    const int*   labels = (const int*)d_in[9];

    char* w = (char*)d_ws;
    float*    G       = (float*)w;                  // 16*32*132 f32 = 270,336 B
    float*    numpart = (float*)(w + 270336);       // 512 f32
    float*    dens    = (float*)(w + 272384);       // 16 f32
    float*    em0f    = (float*)(w + 272448);       // 16*12 f32
    unsigned* counter = (unsigned*)(w + 273216);    // 1 u32
    float*    out     = (float*)d_out;

    k_fused<<<512, 256, 0, stream>>>(seq, Wenc, benc, Wemit, bemit, trans,
                                     startt, endt, lengths, labels,
                                     G, numpart, em0f, counter);
    k_comb<<<B_, 512, 0, stream>>>(startt, endt, em0f, G, numpart,
                                   dens, counter, out);
}